// Round 1
// baseline (757.190 us; speedup 1.0000x reference)
//
#include <hip/hip_runtime.h>

#define CIN    128
#define HH     56
#define WW_    56
#define NBATCH 32
#define COUT   256
#define KTOT   1152   // CIN*9
#define PLANE  3136   // 56*56
#define BM     128    // c_out tile
#define BN     128    // pixel tile
#define BK     32
#define LDK    40     // padded k-stride in LDS (shorts): 80B rows, 16B-aligned frag reads

typedef __attribute__((ext_vector_type(8))) short bf16x8;
typedef __attribute__((ext_vector_type(4))) float f32x4;

__device__ __forceinline__ unsigned short f2bf(float f) {
    unsigned int u = __builtin_bit_cast(unsigned int, f);
    u += 0x7fffu + ((u >> 16) & 1u);   // RNE to bf16
    return (unsigned short)(u >> 16);
}

__global__ __launch_bounds__(256, 2)
void conv_mfma(const float* __restrict__ in,
               const float* __restrict__ wt,
               const float* __restrict__ bias,
               float* __restrict__ out)
{
    // A = weights [c_out][k], B = im2col patches [pix][k] (both k-contiguous)
    __shared__ __align__(16) unsigned short Asm_[BM * LDK];
    __shared__ __align__(16) unsigned short Bsm_[BN * LDK];

    const int t    = threadIdx.x;
    const int pix0 = blockIdx.x * BN;
    const int c0   = blockIdx.y * BM;

    // ---- B-staging coords (fixed per thread across the K loop) ----
    const int pl   = t & 127;          // pixel within tile
    const int kb   = t >> 7;           // k parity (0/1)
    const int pix  = pix0 + pl;
    const int nimg = pix / PLANE;
    const int rem  = pix - nimg * PLANE;
    const int hh   = rem / WW_;
    const int ww   = rem - hh * WW_;
    const float* inbase = in + (size_t)nimg * (CIN * PLANE);

    // ---- A-staging coords ----
    const int acol  = (t & 7) * 4;     // k offset (float4)
    const int arow0 = t >> 3;          // 0..31

    // ---- compute coords ----
    const int lane = t & 63;
    const int wave = t >> 6;
    const int wm   = (wave & 1) * 64;  // c_out offset of this wave
    const int wn   = (wave >> 1) * 64; // pixel offset of this wave
    const int lr   = lane & 15;
    const int quad = lane >> 4;

    f32x4 acc[4][4];
    #pragma unroll
    for (int i = 0; i < 4; ++i)
        #pragma unroll
        for (int j = 0; j < 4; ++j)
            acc[i][j] = (f32x4){0.f, 0.f, 0.f, 0.f};

    for (int k0 = 0; k0 < KTOT; k0 += BK) {
        // stage A: 128x32 weights, float4 coalesced loads, cvt->bf16, packed 8B LDS writes
        #pragma unroll
        for (int p = 0; p < 4; ++p) {
            const int row = arow0 + p * 32;
            const float4 v = *(const float4*)(wt + (size_t)(c0 + row) * KTOT + k0 + acol);
            uint2 pk;
            pk.x = (unsigned)f2bf(v.x) | ((unsigned)f2bf(v.y) << 16);
            pk.y = (unsigned)f2bf(v.z) | ((unsigned)f2bf(v.w) << 16);
            *(uint2*)&Asm_[row * LDK + acol] = pk;
        }
        // stage B: 128x32 on-the-fly im2col gather with zero pad
        #pragma unroll
        for (int it = 0; it < 16; ++it) {
            const int kl = kb + it * 2;
            const int k  = k0 + kl;
            const int ci = k / 9;
            const int r  = k - ci * 9;
            const int kh = r / 3;
            const int kw = r - kh * 3;
            const int hi = hh + kh - 1;
            const int wi = ww + kw - 1;
            float v = 0.f;
            if ((unsigned)hi < HH && (unsigned)wi < WW_)
                v = inbase[ci * PLANE + hi * WW_ + wi];
            Bsm_[pl * LDK + kl] = f2bf(v);
        }
        __syncthreads();

        bf16x8 af[4], bfr[4];
        #pragma unroll
        for (int i = 0; i < 4; ++i)
            af[i] = *(const bf16x8*)&Asm_[(wm + i * 16 + lr) * LDK + quad * 8];
        #pragma unroll
        for (int j = 0; j < 4; ++j)
            bfr[j] = *(const bf16x8*)&Bsm_[(wn + j * 16 + lr) * LDK + quad * 8];

        #pragma unroll
        for (int i = 0; i < 4; ++i)
            #pragma unroll
            for (int j = 0; j < 4; ++j)
                acc[i][j] = __builtin_amdgcn_mfma_f32_16x16x32_bf16(af[i], bfr[j], acc[i][j], 0, 0, 0);
        __syncthreads();
    }

    // epilogue: D[row=c_out][col=pix]; lane holds col=lr, rows quad*4+r
    #pragma unroll
    for (int j = 0; j < 4; ++j) {
        const int pg    = pix0 + wn + j * 16 + lr;
        const int ni    = pg / PLANE;
        const int inner = pg - ni * PLANE;
        float* op = out + (size_t)ni * (COUT * PLANE) + inner;
        #pragma unroll
        for (int i = 0; i < 4; ++i) {
            const int crow = c0 + wm + i * 16 + quad * 4;
            #pragma unroll
            for (int r = 0; r < 4; ++r)
                op[(size_t)(crow + r) * PLANE] = acc[i][j][r] + bias[crow + r];
        }
    }
}

extern "C" void kernel_launch(void* const* d_in, const int* in_sizes, int n_in,
                              void* d_out, int out_size, void* d_ws, size_t ws_size,
                              hipStream_t stream) {
    const float* in   = (const float*)d_in[0];
    const float* wt   = (const float*)d_in[1];
    const float* bias = (const float*)d_in[2];
    float* out        = (float*)d_out;
    dim3 grid((NBATCH * PLANE) / BN, COUT / BM);
    conv_mfma<<<grid, 256, 0, stream>>>(in, wt, bias, out);
}

// Round 2
// 219.086 us; speedup vs baseline: 3.4561x; 3.4561x over previous
//
#include <hip/hip_runtime.h>

#define CIN    128
#define HH     56
#define WW_    56
#define NBATCH 32
#define COUT   256
#define KTOT   1152          // 9 taps * 128 ci  (k-order: kh, kw, ci)
#define PLANE  3136          // 56*56
#define HP     58            // padded H/W
#define BM     128           // c_out tile
#define BN     128           // pixel tile
#define BK     64            // k per step (always within one tap: 1152 = 9*128)

#define WB_OFF   0                         // bf16 weights [256][9][128] in ws
#define WB_BYTES (COUT * KTOT * 2)         // 589824
#define XP_OFF   (1u << 20)                // padded bf16 input [32][58][58][128]
#define XP_BYTES (NBATCH * HP * HP * CIN * 2)  // 27,557,888

typedef __attribute__((ext_vector_type(8))) short bf16x8;
typedef __attribute__((ext_vector_type(4))) float f32x4;

__device__ __forceinline__ unsigned short f2bf(float f) {
    unsigned int u = __builtin_bit_cast(unsigned int, f);
    u += 0x7fffu + ((u >> 16) & 1u);   // RNE
    return (unsigned short)(u >> 16);
}

__device__ __forceinline__ void gl_lds16(const void* g, void* l) {
    __builtin_amdgcn_global_load_lds(
        (const __attribute__((address_space(1))) void*)g,
        (__attribute__((address_space(3))) void*)l, 16, 0, 0);
}

// ---- pre-pass 1: weights OIHW fp32 -> [o][tap][ci] bf16 ----
__global__ void wprep(const float* __restrict__ w, unsigned short* __restrict__ wb) {
    const int o = blockIdx.x;
    const int t = threadIdx.x;
    #pragma unroll
    for (int e = 0; e < 5; ++e) {
        const int k = t + e * 256;
        if (k < KTOT) {
            const int tap = k >> 7;      // kh*3+kw
            const int ci  = k & 127;
            wb[o * KTOT + k] = f2bf(w[(o * CIN + ci) * 9 + tap]);
        }
    }
}

// ---- pre-pass 2: input NCHW fp32 -> padded NHWC bf16 (interior only; border pre-zeroed) ----
__global__ void xprep(const float* __restrict__ in, unsigned short* __restrict__ xp) {
    const int b = blockIdx.x;            // 32*56 blocks: (n, h)
    const int n = b / HH;
    const int h = b - n * HH;
    const int w  = threadIdx.x & 63;
    const int cg = threadIdx.x >> 6;     // 0..3
    if (w >= WW_) return;
    const float* ib = in + ((size_t)n * CIN) * PLANE + h * WW_ + w;
    unsigned short* ob = xp + (((size_t)n * HP + (h + 1)) * HP + (w + 1)) * CIN;
    #pragma unroll
    for (int e = 0; e < 4; ++e) {
        const int chunk = cg + e * 4;    // 16 chunks of 8 ci
        uint4 pk;
        unsigned v[8];
        #pragma unroll
        for (int i = 0; i < 8; ++i)
            v[i] = f2bf(ib[(size_t)(chunk * 8 + i) * PLANE]);
        pk.x = v[0] | (v[1] << 16);
        pk.y = v[2] | (v[3] << 16);
        pk.z = v[4] | (v[5] << 16);
        pk.w = v[6] | (v[7] << 16);
        *(uint4*)(ob + chunk * 8) = pk;
    }
}

// ---- main: implicit-GEMM conv, A=wb[256][1152], B=im2col rows from padded NHWC ----
__global__ __launch_bounds__(256, 2)
void conv_mfma(const unsigned short* __restrict__ wb,
               const unsigned short* __restrict__ xp,
               const float* __restrict__ bias,
               float* __restrict__ out)
{
    __shared__ __align__(16) unsigned short Asm_[BM * BK];  // 16 KB, rows of 128B
    __shared__ __align__(16) unsigned short Bsm_[BN * BK];  // 16 KB

    const int t    = threadIdx.x;
    const int pix0 = blockIdx.x * BN;
    const int c0   = blockIdx.y * BM;

    // staging coords: per issue p (0..3): row = r32 + p*32, physical 16B slot = t&7
    const int slot = t & 7;
    const int r32  = t >> 3;                 // 0..31
    const int swiz = (slot ^ (r32 & 7)) * 16;  // logical-chunk byte offset for this phys slot

    const char* aBase = (const char*)wb + (size_t)(c0 + r32) * (KTOT * 2) + swiz;
    // B pixel bases per issue
    const char* bBase[4];
    #pragma unroll
    for (int p = 0; p < 4; ++p) {
        const int pix = pix0 + r32 + p * 32;
        const int n   = pix / PLANE;
        const int rem = pix - n * PLANE;
        const int h   = rem / WW_;
        const int w   = rem - h * WW_;
        bBase[p] = (const char*)xp + ((size_t)(n * HP + h) * HP + w) * (CIN * 2) + swiz;
    }

    // compute coords
    const int lane = t & 63;
    const int wave = t >> 6;
    const int wm   = (wave & 1) * 64;
    const int wn   = (wave >> 1) * 64;
    const int lr   = lane & 15;
    const int quad = lane >> 4;
    const int rmod = lr & 7;                 // row&7 for all frag rows

    f32x4 acc[4][4];
    #pragma unroll
    for (int i = 0; i < 4; ++i)
        #pragma unroll
        for (int j = 0; j < 4; ++j)
            acc[i][j] = (f32x4){0.f, 0.f, 0.f, 0.f};

    char* const asmb = (char*)Asm_;
    char* const bsmb = (char*)Bsm_;

    for (int tap = 0; tap < 9; ++tap) {
        const int toff = ((tap / 3) * HP + (tap % 3)) * (CIN * 2);  // scalar
        for (int ci0b = 0; ci0b < 256; ci0b += 128) {               // 64-ci halves (bytes)
            const int abyte = tap * 256 + ci0b;
            #pragma unroll
            for (int p = 0; p < 4; ++p)
                gl_lds16(aBase + (size_t)p * 32 * (KTOT * 2) + abyte, asmb + p * 4096 + t * 16);
            #pragma unroll
            for (int p = 0; p < 4; ++p)
                gl_lds16(bBase[p] + toff + ci0b, bsmb + p * 4096 + t * 16);
            __syncthreads();

            #pragma unroll
            for (int kk = 0; kk < 2; ++kk) {
                bf16x8 af[4], bfr[4];
                #pragma unroll
                for (int i = 0; i < 4; ++i) {
                    const int r = wm + i * 16 + lr;
                    const int phys = ((kk * 4 + quad) ^ rmod) * 16;
                    af[i] = *(const bf16x8*)(asmb + r * 128 + phys);
                }
                #pragma unroll
                for (int j = 0; j < 4; ++j) {
                    const int r = wn + j * 16 + lr;
                    const int phys = ((kk * 4 + quad) ^ rmod) * 16;
                    bfr[j] = *(const bf16x8*)(bsmb + r * 128 + phys);
                }
                #pragma unroll
                for (int i = 0; i < 4; ++i)
                    #pragma unroll
                    for (int j = 0; j < 4; ++j)
                        acc[i][j] = __builtin_amdgcn_mfma_f32_16x16x32_bf16(af[i], bfr[j], acc[i][j], 0, 0, 0);
            }
            __syncthreads();
        }
    }

    // epilogue: D[row=c_out][col=pix]; lane: col=lr, rows quad*4+r
    #pragma unroll
    for (int j = 0; j < 4; ++j) {
        const int pg    = pix0 + wn + j * 16 + lr;
        const int ni    = pg / PLANE;
        const int inner = pg - ni * PLANE;
        float* op = out + (size_t)ni * (COUT * PLANE) + inner;
        #pragma unroll
        for (int i = 0; i < 4; ++i) {
            const int crow = c0 + wm + i * 16 + quad * 4;
            #pragma unroll
            for (int r = 0; r < 4; ++r)
                op[(size_t)(crow + r) * PLANE] = acc[i][j][r] + bias[crow + r];
        }
    }
}

extern "C" void kernel_launch(void* const* d_in, const int* in_sizes, int n_in,
                              void* d_out, int out_size, void* d_ws, size_t ws_size,
                              hipStream_t stream) {
    const float* in   = (const float*)d_in[0];
    const float* wt   = (const float*)d_in[1];
    const float* bias = (const float*)d_in[2];
    float* out        = (float*)d_out;

    unsigned short* wb = (unsigned short*)((char*)d_ws + WB_OFF);
    unsigned short* xp = (unsigned short*)((char*)d_ws + XP_OFF);

    // zero the padded input buffer (borders must be 0; ws is poisoned each call)
    hipMemsetAsync(xp, 0, XP_BYTES, stream);
    wprep<<<COUT, 256, 0, stream>>>(wt, wb);
    xprep<<<NBATCH * HH, 256, 0, stream>>>(in, xp);

    dim3 grid((NBATCH * PLANE) / BN, COUT / BM);
    conv_mfma<<<grid, 256, 0, stream>>>(wb, xp, bias, out);
}

// Round 3
// 208.929 us; speedup vs baseline: 3.6241x; 1.0486x over previous
//
#include <hip/hip_runtime.h>

#define CIN    128
#define HH     56
#define WW_    56
#define NBATCH 32
#define COUT   256
#define KTOT   1152          // 9 taps * 128 ci  (k-order: kh, kw, ci)
#define PLANE  3136          // 56*56
#define HP     58            // padded H/W
#define BM     128           // c_out tile
#define BN     128           // pixel tile
#define BK     64            // k per step (always within one tap: 1152 = 9*128)

#define WB_OFF   0                         // bf16 weights [256][9][128] in ws
#define XP_OFF   (1u << 20)                // padded bf16 input [32][58][58][128]

typedef __attribute__((ext_vector_type(8))) short bf16x8;
typedef __attribute__((ext_vector_type(4))) float f32x4;

__device__ __forceinline__ unsigned short f2bf(float f) {
    unsigned int u = __builtin_bit_cast(unsigned int, f);
    u += 0x7fffu + ((u >> 16) & 1u);   // RNE
    return (unsigned short)(u >> 16);
}

__device__ __forceinline__ void gl_lds16(const void* g, void* l) {
    __builtin_amdgcn_global_load_lds(
        (const __attribute__((address_space(1))) void*)g,
        (__attribute__((address_space(3))) void*)l, 16, 0, 0);
}

// ---- pre-pass 1: weights OIHW fp32 -> [o][tap][ci] bf16; contiguous coalesced reads ----
__global__ void wprep(const float* __restrict__ w, unsigned short* __restrict__ wb) {
    const int o = blockIdx.x;
    const int t = threadIdx.x;
    const float* src = w + (size_t)o * KTOT;
    unsigned short* dst = wb + (size_t)o * KTOT;
    #pragma unroll
    for (int e = 0; e < 5; ++e) {
        const int idx = t + e * 256;          // = ci*9 + tap
        if (idx < KTOT) {
            const int ci  = idx / 9;
            const int tap = idx - ci * 9;
            dst[tap * 128 + ci] = f2bf(src[idx]);
        }
    }
}

// ---- pre-pass 2: NCHW fp32 -> padded NHWC bf16, borders written here (no memset) ----
// one block per padded row (n, h_out); coalesced reads AND coalesced uint4 writes
__global__ __launch_bounds__(256)
void xprep(const float* __restrict__ in, unsigned short* __restrict__ xp) {
    const int b  = blockIdx.x;               // n*58 + h_out
    const int n  = b / HP;
    const int ho = b - n * HP;
    const int t  = threadIdx.x;
    uint4* orow = (uint4*)(xp + (((size_t)n * HP + ho) * HP) * CIN);  // 928 uint4 per row

    if (ho == 0 || ho == HP - 1) {
        #pragma unroll
        for (int e = 0; e < 4; ++e) {
            const int idx = t + e * 256;
            if (idx < 928) orow[idx] = (uint4){0u, 0u, 0u, 0u};
        }
        return;
    }

    __shared__ unsigned short L[CIN * 57];   // [ci][w], padded to 57 shorts
    const int h  = ho - 1;
    const int w  = t & 63;
    const int cb = t >> 6;                   // wave id 0..3 -> ci block
    if (w < WW_) {
        const float* ib = in + ((size_t)n * CIN) * PLANE + (size_t)h * WW_ + w;
        #pragma unroll
        for (int e = 0; e < 32; ++e) {
            const int ci = cb * 32 + e;
            L[ci * 57 + w] = f2bf(ib[(size_t)ci * PLANE]);
        }
    }
    __syncthreads();

    #pragma unroll
    for (int e = 0; e < 4; ++e) {
        const int idx = t + e * 256;         // uint4 index within the row
        if (idx < 928) {
            const int wo = idx >> 4;         // pixel 0..57
            const int ch = idx & 15;         // 8-ci chunk
            uint4 pk = {0u, 0u, 0u, 0u};
            if (wo >= 1 && wo <= WW_) {
                const int wi = wo - 1;
                unsigned v[8];
                #pragma unroll
                for (int i = 0; i < 8; ++i)
                    v[i] = L[(ch * 8 + i) * 57 + wi];
                pk.x = v[0] | (v[1] << 16);
                pk.y = v[2] | (v[3] << 16);
                pk.z = v[4] | (v[5] << 16);
                pk.w = v[6] | (v[7] << 16);
            }
            orow[idx] = pk;
        }
    }
}

// ---- main: implicit-GEMM conv, A=wb[256][1152], B=im2col rows from padded NHWC ----
__global__ __launch_bounds__(256, 2)
void conv_mfma(const unsigned short* __restrict__ wb,
               const unsigned short* __restrict__ xp,
               const float* __restrict__ bias,
               float* __restrict__ out)
{
    __shared__ __align__(16) unsigned short Asm_[BM * BK];  // 16 KB, rows of 128B
    __shared__ __align__(16) unsigned short Bsm_[BN * BK];  // 16 KB

    const int t    = threadIdx.x;
    const int pix0 = blockIdx.x * BN;
    const int c0   = blockIdx.y * BM;

    const int slot = t & 7;
    const int r32  = t >> 3;                 // 0..31
    const int swiz = (slot ^ (r32 & 7)) * 16;

    const char* aBase = (const char*)wb + (size_t)(c0 + r32) * (KTOT * 2) + swiz;
    const char* bBase[4];
    #pragma unroll
    for (int p = 0; p < 4; ++p) {
        const int pix = pix0 + r32 + p * 32;
        const int n   = pix / PLANE;
        const int rem = pix - n * PLANE;
        const int h   = rem / WW_;
        const int w   = rem - h * WW_;
        bBase[p] = (const char*)xp + ((size_t)(n * HP + h) * HP + w) * (CIN * 2) + swiz;
    }

    const int lane = t & 63;
    const int wave = t >> 6;
    const int wm   = (wave & 1) * 64;
    const int wn   = (wave >> 1) * 64;
    const int lr   = lane & 15;
    const int quad = lane >> 4;
    const int rmod = lr & 7;

    f32x4 acc[4][4];
    #pragma unroll
    for (int i = 0; i < 4; ++i)
        #pragma unroll
        for (int j = 0; j < 4; ++j)
            acc[i][j] = (f32x4){0.f, 0.f, 0.f, 0.f};

    char* const asmb = (char*)Asm_;
    char* const bsmb = (char*)Bsm_;

    for (int tap = 0; tap < 9; ++tap) {
        const int toff = ((tap / 3) * HP + (tap % 3)) * (CIN * 2);
        for (int ci0b = 0; ci0b < 256; ci0b += 128) {
            const int abyte = tap * 256 + ci0b;
            #pragma unroll
            for (int p = 0; p < 4; ++p)
                gl_lds16(aBase + (size_t)p * 32 * (KTOT * 2) + abyte, asmb + p * 4096 + t * 16);
            #pragma unroll
            for (int p = 0; p < 4; ++p)
                gl_lds16(bBase[p] + toff + ci0b, bsmb + p * 4096 + t * 16);
            __syncthreads();

            #pragma unroll
            for (int kk = 0; kk < 2; ++kk) {
                bf16x8 af[4], bfr[4];
                #pragma unroll
                for (int i = 0; i < 4; ++i) {
                    const int r = wm + i * 16 + lr;
                    const int phys = ((kk * 4 + quad) ^ rmod) * 16;
                    af[i] = *(const bf16x8*)(asmb + r * 128 + phys);
                }
                #pragma unroll
                for (int j = 0; j < 4; ++j) {
                    const int r = wn + j * 16 + lr;
                    const int phys = ((kk * 4 + quad) ^ rmod) * 16;
                    bfr[j] = *(const bf16x8*)(bsmb + r * 128 + phys);
                }
                #pragma unroll
                for (int i = 0; i < 4; ++i)
                    #pragma unroll
                    for (int j = 0; j < 4; ++j)
                        acc[i][j] = __builtin_amdgcn_mfma_f32_16x16x32_bf16(af[i], bfr[j], acc[i][j], 0, 0, 0);
            }
            __syncthreads();
        }
    }

    #pragma unroll
    for (int j = 0; j < 4; ++j) {
        const int pg    = pix0 + wn + j * 16 + lr;
        const int ni    = pg / PLANE;
        const int inner = pg - ni * PLANE;
        float* op = out + (size_t)ni * (COUT * PLANE) + inner;
        #pragma unroll
        for (int i = 0; i < 4; ++i) {
            const int crow = c0 + wm + i * 16 + quad * 4;
            #pragma unroll
            for (int r = 0; r < 4; ++r)
                op[(size_t)(crow + r) * PLANE] = acc[i][j][r] + bias[crow + r];
        }
    }
}

extern "C" void kernel_launch(void* const* d_in, const int* in_sizes, int n_in,
                              void* d_out, int out_size, void* d_ws, size_t ws_size,
                              hipStream_t stream) {
    const float* in   = (const float*)d_in[0];
    const float* wt   = (const float*)d_in[1];
    const float* bias = (const float*)d_in[2];
    float* out        = (float*)d_out;

    unsigned short* wb = (unsigned short*)((char*)d_ws + WB_OFF);
    unsigned short* xp = (unsigned short*)((char*)d_ws + XP_OFF);

    wprep<<<COUT, 256, 0, stream>>>(wt, wb);
    xprep<<<NBATCH * HP, 256, 0, stream>>>(in, xp);

    dim3 grid((NBATCH * PLANE) / BN, COUT / BM);
    conv_mfma<<<grid, 256, 0, stream>>>(wb, xp, bias, out);
}